// Round 1
// baseline (148.857 us; speedup 1.0000x reference)
//
#include <hip/hip_runtime.h>
#include <hip/hip_bf16.h>

#define N_V   20000
#define KNB   16
#define DCODE 256
#define H1    512
#define H2    1024
#define M3    60000   // N_V * 3

// ws layout (float offsets)
#define OFF_L1P   0          // 8*512   = 4096
#define OFF_L2P   4096       // 8*1024  = 8192 -> 12288
#define OFF_VPART 12288      // 4*60000 = 240000 -> 252288
#define OFF_V     252288     // 60000 -> 312288
#define OFF_GV    312288     // 60000 -> 372288
#define OFF_GZ2   372288     // 1024  -> 373312
#define OFF_GZ1   373312     // 512   -> 373824
#define OFF_H1    373824     // 512   -> 374336
#define OFF_H2    374336     // 1024  -> 375360
#define OFF_E     375360     // double (2 float slots)

// ---------------- decoder forward ----------------

// grid (2, 8), block 256: partial z1 over 32-d chunks
__global__ void k_l1p(const float* __restrict__ code, const float* __restrict__ W1,
                      float* __restrict__ ws) {
    int m = blockIdx.x * 256 + threadIdx.x;     // < 512
    int d0 = blockIdx.y * 32;
    float acc = 0.f;
#pragma unroll
    for (int d = 0; d < 32; ++d)
        acc += code[d0 + d] * W1[(size_t)(d0 + d) * H1 + m];
    ws[OFF_L1P + blockIdx.y * H1 + m] = acc;
}

// grid (4, 8), block 256: reduce l1 partials for own d-chunk, partial z2
__global__ void k_l2p(const float* __restrict__ b1, const float* __restrict__ W2,
                      float* __restrict__ ws) {
    __shared__ float h1s[64];
    int dz = blockIdx.y, d0 = dz * 64;
    int t = threadIdx.x;
    if (t < 64) {
        float s = b1[d0 + t];
#pragma unroll
        for (int p = 0; p < 8; ++p) s += ws[OFF_L1P + p * H1 + d0 + t];
        float h = fmaxf(s, 0.f);
        h1s[t] = h;
        if (blockIdx.x == 0) ws[OFF_H1 + d0 + t] = h;
    }
    __syncthreads();
    int m = blockIdx.x * 256 + t;               // < 1024
    float acc = 0.f;
#pragma unroll 8
    for (int d = 0; d < 64; ++d)
        acc += h1s[d] * W2[(size_t)(d0 + d) * H2 + m];
    ws[OFF_L2P + dz * H2 + m] = acc;
}

// grid (59, 4), block 256: reduce l2 partials for own j-chunk, partial v (float4, relu row skip)
__global__ void k_l3p(const float* __restrict__ b2, const float* __restrict__ W3,
                      float* __restrict__ ws) {
    __shared__ float h2s[256];
    int jz = blockIdx.y, j0 = jz * 256;
    int t = threadIdx.x;
    {
        float s = b2[j0 + t];
#pragma unroll
        for (int p = 0; p < 8; ++p) s += ws[OFF_L2P + p * H2 + j0 + t];
        float h = fmaxf(s, 0.f);
        h2s[t] = h;
        if (blockIdx.x == 0) ws[OFF_H2 + j0 + t] = h;
    }
    __syncthreads();
    int m4 = blockIdx.x * 1024 + t * 4;
    if (m4 < M3) {
        float4 acc = make_float4(0.f, 0.f, 0.f, 0.f);
        for (int j = 0; j < 256; ++j) {
            float h = h2s[j];
            if (h != 0.f) {
                const float4 wv = *reinterpret_cast<const float4*>(
                    &W3[(size_t)(j0 + j) * M3 + m4]);
                acc.x += h * wv.x; acc.y += h * wv.y;
                acc.z += h * wv.z; acc.w += h * wv.w;
            }
        }
        *reinterpret_cast<float4*>(&ws[OFF_VPART + jz * M3 + m4]) = acc;
    }
}

// grid 59, block 256: v = b3 + sum of 4 partials
__global__ void k_vred(const float* __restrict__ b3, float* __restrict__ ws) {
    int i4 = blockIdx.x * 256 + threadIdx.x;
    if (i4 < M3 / 4) {
        int m = i4 * 4;
        float4 a = *reinterpret_cast<const float4*>(&b3[m]);
#pragma unroll
        for (int jz = 0; jz < 4; ++jz) {
            float4 p = *reinterpret_cast<const float4*>(&ws[OFF_VPART + jz * M3 + m]);
            a.x += p.x; a.y += p.y; a.z += p.z; a.w += p.w;
        }
        *reinterpret_cast<float4*>(&ws[OFF_V + m]) = a;
    }
}

// ---------------- ARAP per-vertex (f64 internals) ----------------

__device__ inline void jrot(double a[3][3], double v[3][3], int p, int q) {
    double apq = a[p][q];
    if (fabs(apq) < 1e-300) return;
    double theta = (a[q][q] - a[p][p]) / (2.0 * apq);
    double t;
    if (fabs(theta) > 1.0e100) t = 0.5 / theta;
    else t = copysign(1.0, theta) / (fabs(theta) + sqrt(theta * theta + 1.0));
    double c = 1.0 / sqrt(t * t + 1.0);
    double s = t * c;
    double app = a[p][p], aqq = a[q][q];
    a[p][p] = app - t * apq;
    a[q][q] = aqq + t * apq;
    a[p][q] = 0.0; a[q][p] = 0.0;
    int r = 3 - p - q;
    double arp = a[r][p], arq = a[r][q];
    a[r][p] = c * arp - s * arq; a[p][r] = a[r][p];
    a[r][q] = s * arp + c * arq; a[q][r] = a[r][q];
#pragma unroll
    for (int k2 = 0; k2 < 3; ++k2) {
        double vkp = v[k2][p], vkq = v[k2][q];
        v[k2][p] = c * vkp - s * vkq;
        v[k2][q] = s * vkp + c * vkq;
    }
}

// R = V diag(1,1,d) U^T from S = U S V^T (ARAP proper-rotation fit)
__device__ void compute_R(const double S[3][3], double R[3][3]) {
    double A[3][3], V[3][3];
#pragma unroll
    for (int a = 0; a < 3; ++a)
#pragma unroll
        for (int b = 0; b < 3; ++b) {
            double s = 0.0;
#pragma unroll
            for (int c = 0; c < 3; ++c) s += S[c][a] * S[c][b];
            A[a][b] = s;
            V[a][b] = (a == b) ? 1.0 : 0.0;
        }
    for (int sweep = 0; sweep < 20; ++sweep) {
        double off = A[0][1]*A[0][1] + A[0][2]*A[0][2] + A[1][2]*A[1][2];
        double dg  = A[0][0]*A[0][0] + A[1][1]*A[1][1] + A[2][2]*A[2][2];
        if (off <= 1e-28 * (dg + 1e-300)) break;
        jrot(A, V, 0, 1); jrot(A, V, 0, 2); jrot(A, V, 1, 2);
    }
    int id[3] = {0, 1, 2};
    if (A[id[0]][id[0]] < A[id[1]][id[1]]) { int t = id[0]; id[0] = id[1]; id[1] = t; }
    if (A[id[0]][id[0]] < A[id[2]][id[2]]) { int t = id[0]; id[0] = id[2]; id[2] = t; }
    if (A[id[1]][id[1]] < A[id[2]][id[2]]) { int t = id[1]; id[1] = id[2]; id[2] = t; }
    double v0[3], v1[3], v2[3];
#pragma unroll
    for (int r = 0; r < 3; ++r) {
        v0[r] = V[r][id[0]]; v1[r] = V[r][id[1]]; v2[r] = V[r][id[2]];
    }
    double u0[3], u1[3], u2[3];
#pragma unroll
    for (int a = 0; a < 3; ++a)
        u0[a] = S[a][0]*v0[0] + S[a][1]*v0[1] + S[a][2]*v0[2];
    double n0 = sqrt(u0[0]*u0[0] + u0[1]*u0[1] + u0[2]*u0[2]);
    if (!(n0 > 1e-150)) {  // S ~ 0: any rotation; reference (svd of 0) gives I
#pragma unroll
        for (int a = 0; a < 3; ++a)
#pragma unroll
            for (int c = 0; c < 3; ++c) R[a][c] = (a == c) ? 1.0 : 0.0;
        return;
    }
#pragma unroll
    for (int a = 0; a < 3; ++a) u0[a] /= n0;
    double t1[3];
#pragma unroll
    for (int a = 0; a < 3; ++a)
        t1[a] = S[a][0]*v1[0] + S[a][1]*v1[1] + S[a][2]*v1[2];
    double dp = u0[0]*t1[0] + u0[1]*t1[1] + u0[2]*t1[2];
#pragma unroll
    for (int a = 0; a < 3; ++a) t1[a] -= dp * u0[a];
    double n1 = sqrt(t1[0]*t1[0] + t1[1]*t1[1] + t1[2]*t1[2]);
    if (n1 > 1e-9 * n0) {
#pragma unroll
        for (int a = 0; a < 3; ++a) u1[a] = t1[a] / n1;
    } else {
        int m = (fabs(u0[0]) <= fabs(u0[1]) && fabs(u0[0]) <= fabs(u0[2])) ? 0
              : (fabs(u0[1]) <= fabs(u0[2]) ? 1 : 2);
        double e[3] = {0.0, 0.0, 0.0}; e[m] = 1.0;
        double cx[3] = { u0[1]*e[2] - u0[2]*e[1],
                         u0[2]*e[0] - u0[0]*e[2],
                         u0[0]*e[1] - u0[1]*e[0] };
        double nn = sqrt(cx[0]*cx[0] + cx[1]*cx[1] + cx[2]*cx[2]);
#pragma unroll
        for (int a = 0; a < 3; ++a) u1[a] = cx[a] / nn;
    }
    u2[0] = u0[1]*u1[2] - u0[2]*u1[1];
    u2[1] = u0[2]*u1[0] - u0[0]*u1[2];
    u2[2] = u0[0]*u1[1] - u0[1]*u1[0];
    // d = det([v0 v1 v2]) * det(U); det(U)=+1 by construction
    double d = v0[0]*(v1[1]*v2[2] - v1[2]*v2[1])
             - v0[1]*(v1[0]*v2[2] - v1[2]*v2[0])
             + v0[2]*(v1[0]*v2[1] - v1[1]*v2[0]);
#pragma unroll
    for (int a = 0; a < 3; ++a)
#pragma unroll
        for (int c = 0; c < 3; ++c)
            R[a][c] = v0[a]*u0[c] + v1[a]*u1[c] + d * (v2[a]*u2[c]);
}

// grid 79, block 256
__global__ void k_arap(const float* __restrict__ xyz1, const float* __restrict__ wmat,
                       const int* __restrict__ nbr, const int* __restrict__ nnum,
                       float* __restrict__ ws) {
    const float* recon = ws + OFF_V;
    float* gv = ws + OFF_GV;
    int i = blockIdx.x * 256 + threadIdx.x;
    double pv = 0.0;
    if (i < N_V) {
        int num = nnum[i];
        if (num > KNB) num = KNB;
        double cr0 = xyz1[3*i], cr1 = xyz1[3*i+1], cr2 = xyz1[3*i+2];
        double cd0 = recon[3*i], cd1 = recon[3*i+1], cd2 = recon[3*i+2];
        double S[3][3] = {{0,0,0},{0,0,0},{0,0,0}};
        for (int k = 0; k < num; ++k) {
            int j = nbr[i*KNB + k];
            double w = wmat[i*KNB + k];
            double er[3] = { xyz1[3*j] - cr0, xyz1[3*j+1] - cr1, xyz1[3*j+2] - cr2 };
            double ed[3] = { recon[3*j] - cd0, recon[3*j+1] - cd1, recon[3*j+2] - cd2 };
#pragma unroll
            for (int a = 0; a < 3; ++a)
#pragma unroll
                for (int b = 0; b < 3; ++b) S[a][b] += w * er[a] * ed[b];
        }
        double R[3][3];
        compute_R(S, R);
        const float gscale = 2.0f / (float)N_V;
        for (int k = 0; k < num; ++k) {
            int j = nbr[i*KNB + k];
            double w = wmat[i*KNB + k];
            double er[3] = { xyz1[3*j] - cr0, xyz1[3*j+1] - cr1, xyz1[3*j+2] - cr2 };
            double ed[3] = { recon[3*j] - cd0, recon[3*j+1] - cd1, recon[3*j+2] - cd2 };
            double rr0 = R[0][0]*er[0] + R[0][1]*er[1] + R[0][2]*er[2];
            double rr1 = R[1][0]*er[0] + R[1][1]*er[1] + R[1][2]*er[2];
            double rr2 = R[2][0]*er[0] + R[2][1]*er[1] + R[2][2]*er[2];
            double r0 = ed[0] - rr0, r1 = ed[1] - rr1, r2 = ed[2] - rr2;
            pv += w * (r0*r0 + r1*r1 + r2*r2);
            float g0 = gscale * (float)(w * r0);
            float g1 = gscale * (float)(w * r1);
            float g2 = gscale * (float)(w * r2);
            atomicAdd(&gv[3*j+0],  g0);
            atomicAdd(&gv[3*j+1],  g1);
            atomicAdd(&gv[3*j+2],  g2);
            atomicAdd(&gv[3*i+0], -g0);
            atomicAdd(&gv[3*i+1], -g1);
            atomicAdd(&gv[3*i+2], -g2);
        }
    }
    __shared__ double red[256];
    red[threadIdx.x] = pv;
    __syncthreads();
    for (int s = 128; s > 0; s >>= 1) {
        if (threadIdx.x < s) red[threadIdx.x] += red[threadIdx.x + s];
        __syncthreads();
    }
    if (threadIdx.x == 0)
        atomicAdd(reinterpret_cast<double*>(ws + OFF_E), red[0]);
}

// ---------------- backward ----------------

// grid 1024, block 256: g_z2[j] = (h2[j]>0) * dot(W3[j,:], g_v)
__global__ void k_gh2(const float* __restrict__ W3, float* __restrict__ ws) {
    int j = blockIdx.x;
    float* gz2 = ws + OFF_GZ2;
    float h2v = ws[OFF_H2 + j];
    if (h2v <= 0.f) {
        if (threadIdx.x == 0) gz2[j] = 0.f;
        return;
    }
    const float4* w3r = reinterpret_cast<const float4*>(W3 + (size_t)j * M3);
    const float4* gv4 = reinterpret_cast<const float4*>(ws + OFF_GV);
    float acc = 0.f;
    for (int it = threadIdx.x; it < M3 / 4; it += 256) {
        float4 a = w3r[it], b = gv4[it];
        acc += a.x*b.x + a.y*b.y + a.z*b.z + a.w*b.w;
    }
    for (int m = 32; m; m >>= 1) acc += __shfl_xor(acc, m);
    __shared__ float wsum[4];
    if ((threadIdx.x & 63) == 0) wsum[threadIdx.x >> 6] = acc;
    __syncthreads();
    if (threadIdx.x == 0) gz2[j] = wsum[0] + wsum[1] + wsum[2] + wsum[3];
}

// grid 128, block 256 (wave per row): g_z1[i] = (h1[i]>0) * dot(W2[i,:], g_z2)
__global__ void k_gh1(const float* __restrict__ W2, float* __restrict__ ws) {
    int wv = threadIdx.x >> 6, ln = threadIdx.x & 63;
    int i = blockIdx.x * 4 + wv;  // < 512
    const float* gz2 = ws + OFF_GZ2;
    float acc = 0.f;
#pragma unroll
    for (int it = 0; it < H2 / 64; ++it) {
        int jj = ln + it * 64;
        acc += W2[(size_t)i * H2 + jj] * gz2[jj];
    }
    for (int m = 32; m; m >>= 1) acc += __shfl_xor(acc, m);
    if (ln == 0) ws[OFF_GZ1 + i] = (ws[OFF_H1 + i] > 0.f) ? acc : 0.f;
}

// grid 64, block 256 (wave per row): out[1+d] = dot(W1[d,:], g_z1); out[0] = -E/N
__global__ void k_gcode(const float* __restrict__ W1, float* __restrict__ ws,
                        float* __restrict__ out) {
    int wv = threadIdx.x >> 6, ln = threadIdx.x & 63;
    int d = blockIdx.x * 4 + wv;  // < 256
    const float* gz1 = ws + OFF_GZ1;
    float acc = 0.f;
#pragma unroll
    for (int it = 0; it < H1 / 64; ++it) {
        int ii = ln + it * 64;
        acc += W1[(size_t)d * H1 + ii] * gz1[ii];
    }
    for (int m = 32; m; m >>= 1) acc += __shfl_xor(acc, m);
    if (ln == 0) out[1 + d] = acc;
    if (blockIdx.x == 0 && threadIdx.x == 0) {
        double E = *reinterpret_cast<const double*>(ws + OFF_E);
        out[0] = (float)(-(E / (double)N_V));
    }
}

extern "C" void kernel_launch(void* const* d_in, const int* in_sizes, int n_in,
                              void* d_out, int out_size, void* d_ws, size_t ws_size,
                              hipStream_t stream) {
    const float* code = (const float*)d_in[0];
    const float* xyz1 = (const float*)d_in[1];
    const float* wmat = (const float*)d_in[2];
    const float* W1   = (const float*)d_in[3];
    const float* b1   = (const float*)d_in[4];
    const float* W2   = (const float*)d_in[5];
    const float* b2   = (const float*)d_in[6];
    const float* W3   = (const float*)d_in[7];
    const float* b3   = (const float*)d_in[8];
    const int*   nbr  = (const int*)d_in[9];
    const int*   nnum = (const int*)d_in[10];
    float* out = (float*)d_out;
    float* ws  = (float*)d_ws;

    hipMemsetAsync(ws + OFF_GV, 0, M3 * sizeof(float), stream);
    hipMemsetAsync(ws + OFF_E,  0, 2 * sizeof(float), stream);

    k_l1p  <<<dim3(2, 8),  256, 0, stream>>>(code, W1, ws);
    k_l2p  <<<dim3(4, 8),  256, 0, stream>>>(b1, W2, ws);
    k_l3p  <<<dim3(59, 4), 256, 0, stream>>>(b2, W3, ws);
    k_vred <<<59,          256, 0, stream>>>(b3, ws);
    k_arap <<<79,          256, 0, stream>>>(xyz1, wmat, nbr, nnum, ws);
    k_gh2  <<<1024,        256, 0, stream>>>(W3, ws);
    k_gh1  <<<128,         256, 0, stream>>>(W2, ws);
    k_gcode<<<64,          256, 0, stream>>>(W1, ws, out);
}

// Round 2
// 117.507 us; speedup vs baseline: 1.2668x; 1.2668x over previous
//
#include <hip/hip_runtime.h>
#include <hip/hip_bf16.h>

#define N_V   20000
#define KNB   16
#define DCODE 256
#define H1    512
#define H2    1024
#define M3    60000   // N_V * 3

// ws layout (float offsets)
#define OFF_L1P   0          // 8*512 -> 4096
#define OFF_L2P   4096       // 8*1024 -> 12288
#define OFF_VPART 12288      // 8*60000 -> 492288
#define OFF_V     492288     // 60000 -> 552288
#define OFF_GV    552288     // 60000 -> 612288
#define OFF_GZ2   612288     // 1024 -> 613312
#define OFF_GZ1   613312     // 512  -> 613824
#define OFF_H1    613824     // 512  -> 614336
#define OFF_H2    614336     // 1024 -> 615360
#define OFF_HC    615360     // 1024 compacted h2 values -> 616384
#define OFF_LIST  616384     // 1024 ints -> 617408
#define OFF_CNT   617408     // 1 int
#define OFF_E     617410     // double (2 float slots, 8B-aligned)

// ---------------- decoder forward ----------------

// grid (2, 8), block 256: partial z1 over 32-d chunks; also zero gv and E
__global__ void k_l1p(const float* __restrict__ code, const float* __restrict__ W1,
                      float* __restrict__ ws) {
    int m = blockIdx.x * 256 + threadIdx.x;     // < 512
    int d0 = blockIdx.y * 32;
    float acc = 0.f;
#pragma unroll
    for (int d = 0; d < 32; ++d)
        acc += code[d0 + d] * W1[(size_t)(d0 + d) * H1 + m];
    ws[OFF_L1P + blockIdx.y * H1 + m] = acc;
    // zero gradient buffer + energy accumulator (16 blocks x 256 = 4096 threads)
    int gid = (blockIdx.y * 2 + blockIdx.x) * 256 + threadIdx.x;
    for (int idx = gid; idx < M3; idx += 4096) ws[OFF_GV + idx] = 0.f;
    if (gid == 0) { ws[OFF_E] = 0.f; ws[OFF_E + 1] = 0.f; }
}

// grid (4, 8), block 256: reduce l1 partials for own d-chunk, partial z2
__global__ void k_l2p(const float* __restrict__ b1, const float* __restrict__ W2,
                      float* __restrict__ ws) {
    __shared__ float h1s[64];
    int dz = blockIdx.y, d0 = dz * 64;
    int t = threadIdx.x;
    if (t < 64) {
        float s = b1[d0 + t];
#pragma unroll
        for (int p = 0; p < 8; ++p) s += ws[OFF_L1P + p * H1 + d0 + t];
        float h = fmaxf(s, 0.f);
        h1s[t] = h;
        if (blockIdx.x == 0) ws[OFF_H1 + d0 + t] = h;
    }
    __syncthreads();
    int m = blockIdx.x * 256 + t;               // < 1024
    float acc = 0.f;
#pragma unroll 8
    for (int d = 0; d < 64; ++d)
        acc += h1s[d] * W2[(size_t)(d0 + d) * H2 + m];
    ws[OFF_L2P + dz * H2 + m] = acc;
}

// 1 block, 256 threads: finalize h2 = relu(z2), compact nonzero rows into LIST/HC
__global__ void k_compact(const float* __restrict__ b2, float* __restrict__ ws) {
    __shared__ int scan[256];
    int t = threadIdx.x;
    float h[4]; int c = 0;
#pragma unroll
    for (int q = 0; q < 4; ++q) {
        int j = t * 4 + q;
        float s = b2[j];
#pragma unroll
        for (int p = 0; p < 8; ++p) s += ws[OFF_L2P + p * H2 + j];
        float hv = fmaxf(s, 0.f);
        ws[OFF_H2 + j] = hv;
        h[q] = hv;
        c += (hv > 0.f) ? 1 : 0;
    }
    scan[t] = c;
    __syncthreads();
    for (int off = 1; off < 256; off <<= 1) {
        int x = (t >= off) ? scan[t - off] : 0;
        __syncthreads();
        scan[t] += x;
        __syncthreads();
    }
    int base = scan[t] - c;
    int* list = reinterpret_cast<int*>(&ws[OFF_LIST]);
#pragma unroll
    for (int q = 0; q < 4; ++q) {
        if (h[q] > 0.f) {
            list[base] = t * 4 + q;
            ws[OFF_HC + base] = h[q];
            ++base;
        }
    }
    if (t == 255) *reinterpret_cast<int*>(&ws[OFF_CNT]) = scan[255];
}

// grid (59, 8), block 256: partial v over compacted-row chunks (unconditional, unrolled x4)
__global__ void k_l3p(const float* __restrict__ W3, float* __restrict__ ws) {
    __shared__ int   rlist[128];
    __shared__ float rh[128];
    int jz = blockIdx.y;
    int cnt = *reinterpret_cast<const int*>(&ws[OFF_CNT]);
    int per = (cnt + 7) >> 3;                    // <= 128
    int s0 = jz * per;
    int s1 = s0 + per; if (s1 > cnt) s1 = cnt;
    int n = s1 - s0;                              // may be <= 0
    int t = threadIdx.x;
    if (t < 128 && t < n) {
        rlist[t] = reinterpret_cast<const int*>(&ws[OFF_LIST])[s0 + t];
        rh[t]    = ws[OFF_HC + s0 + t];
    }
    __syncthreads();
    int m4 = blockIdx.x * 1024 + t * 4;
    if (m4 >= M3) return;
    float ax = 0.f, ay = 0.f, az = 0.f, aw = 0.f;
    int ii = 0;
    for (; ii + 3 < n; ii += 4) {
        int r0 = rlist[ii], r1 = rlist[ii + 1], r2 = rlist[ii + 2], r3 = rlist[ii + 3];
        float h0 = rh[ii], h1v = rh[ii + 1], h2v = rh[ii + 2], h3 = rh[ii + 3];
        float4 w0 = *reinterpret_cast<const float4*>(&W3[(size_t)r0 * M3 + m4]);
        float4 w1 = *reinterpret_cast<const float4*>(&W3[(size_t)r1 * M3 + m4]);
        float4 w2 = *reinterpret_cast<const float4*>(&W3[(size_t)r2 * M3 + m4]);
        float4 w3 = *reinterpret_cast<const float4*>(&W3[(size_t)r3 * M3 + m4]);
        ax += h0 * w0.x + h1v * w1.x + h2v * w2.x + h3 * w3.x;
        ay += h0 * w0.y + h1v * w1.y + h2v * w2.y + h3 * w3.y;
        az += h0 * w0.z + h1v * w1.z + h2v * w2.z + h3 * w3.z;
        aw += h0 * w0.w + h1v * w1.w + h2v * w2.w + h3 * w3.w;
    }
    for (; ii < n; ++ii) {
        int r0 = rlist[ii]; float h0 = rh[ii];
        float4 w0 = *reinterpret_cast<const float4*>(&W3[(size_t)r0 * M3 + m4]);
        ax += h0 * w0.x; ay += h0 * w0.y; az += h0 * w0.z; aw += h0 * w0.w;
    }
    float4 acc = make_float4(ax, ay, az, aw);
    *reinterpret_cast<float4*>(&ws[OFF_VPART + jz * M3 + m4]) = acc;
}

// grid 59, block 256: v = b3 + sum of 8 partials
__global__ void k_vred(const float* __restrict__ b3, float* __restrict__ ws) {
    int i4 = blockIdx.x * 256 + threadIdx.x;
    if (i4 < M3 / 4) {
        int m = i4 * 4;
        float4 a = *reinterpret_cast<const float4*>(&b3[m]);
#pragma unroll
        for (int jz = 0; jz < 8; ++jz) {
            float4 p = *reinterpret_cast<const float4*>(&ws[OFF_VPART + jz * M3 + m]);
            a.x += p.x; a.y += p.y; a.z += p.z; a.w += p.w;
        }
        *reinterpret_cast<float4*>(&ws[OFF_V + m]) = a;
    }
}

// ---------------- ARAP per-vertex (f64 internals) ----------------

__device__ inline void jrot(double a[3][3], double v[3][3], int p, int q) {
    double apq = a[p][q];
    if (fabs(apq) < 1e-300) return;
    double theta = (a[q][q] - a[p][p]) / (2.0 * apq);
    double t;
    if (fabs(theta) > 1.0e100) t = 0.5 / theta;
    else t = copysign(1.0, theta) / (fabs(theta) + sqrt(theta * theta + 1.0));
    double c = 1.0 / sqrt(t * t + 1.0);
    double s = t * c;
    double app = a[p][p], aqq = a[q][q];
    a[p][p] = app - t * apq;
    a[q][q] = aqq + t * apq;
    a[p][q] = 0.0; a[q][p] = 0.0;
    int r = 3 - p - q;
    double arp = a[r][p], arq = a[r][q];
    a[r][p] = c * arp - s * arq; a[p][r] = a[r][p];
    a[r][q] = s * arp + c * arq; a[q][r] = a[r][q];
#pragma unroll
    for (int k2 = 0; k2 < 3; ++k2) {
        double vkp = v[k2][p], vkq = v[k2][q];
        v[k2][p] = c * vkp - s * vkq;
        v[k2][q] = s * vkp + c * vkq;
    }
}

// R = V diag(1,1,d) U^T from S = U S V^T (ARAP proper-rotation fit)
__device__ void compute_R(const double S[3][3], double R[3][3]) {
    double A[3][3], V[3][3];
#pragma unroll
    for (int a = 0; a < 3; ++a)
#pragma unroll
        for (int b = 0; b < 3; ++b) {
            double s = 0.0;
#pragma unroll
            for (int c = 0; c < 3; ++c) s += S[c][a] * S[c][b];
            A[a][b] = s;
            V[a][b] = (a == b) ? 1.0 : 0.0;
        }
    for (int sweep = 0; sweep < 20; ++sweep) {
        double off = A[0][1]*A[0][1] + A[0][2]*A[0][2] + A[1][2]*A[1][2];
        double dg  = A[0][0]*A[0][0] + A[1][1]*A[1][1] + A[2][2]*A[2][2];
        if (off <= 1e-28 * (dg + 1e-300)) break;
        jrot(A, V, 0, 1); jrot(A, V, 0, 2); jrot(A, V, 1, 2);
    }
    int id[3] = {0, 1, 2};
    if (A[id[0]][id[0]] < A[id[1]][id[1]]) { int t = id[0]; id[0] = id[1]; id[1] = t; }
    if (A[id[0]][id[0]] < A[id[2]][id[2]]) { int t = id[0]; id[0] = id[2]; id[2] = t; }
    if (A[id[1]][id[1]] < A[id[2]][id[2]]) { int t = id[1]; id[1] = id[2]; id[2] = t; }
    double v0[3], v1[3], v2[3];
#pragma unroll
    for (int r = 0; r < 3; ++r) {
        v0[r] = V[r][id[0]]; v1[r] = V[r][id[1]]; v2[r] = V[r][id[2]];
    }
    double u0[3], u1[3], u2[3];
#pragma unroll
    for (int a = 0; a < 3; ++a)
        u0[a] = S[a][0]*v0[0] + S[a][1]*v0[1] + S[a][2]*v0[2];
    double n0 = sqrt(u0[0]*u0[0] + u0[1]*u0[1] + u0[2]*u0[2]);
    if (!(n0 > 1e-150)) {
#pragma unroll
        for (int a = 0; a < 3; ++a)
#pragma unroll
            for (int c = 0; c < 3; ++c) R[a][c] = (a == c) ? 1.0 : 0.0;
        return;
    }
#pragma unroll
    for (int a = 0; a < 3; ++a) u0[a] /= n0;
    double t1[3];
#pragma unroll
    for (int a = 0; a < 3; ++a)
        t1[a] = S[a][0]*v1[0] + S[a][1]*v1[1] + S[a][2]*v1[2];
    double dp = u0[0]*t1[0] + u0[1]*t1[1] + u0[2]*t1[2];
#pragma unroll
    for (int a = 0; a < 3; ++a) t1[a] -= dp * u0[a];
    double n1 = sqrt(t1[0]*t1[0] + t1[1]*t1[1] + t1[2]*t1[2]);
    if (n1 > 1e-9 * n0) {
#pragma unroll
        for (int a = 0; a < 3; ++a) u1[a] = t1[a] / n1;
    } else {
        int m = (fabs(u0[0]) <= fabs(u0[1]) && fabs(u0[0]) <= fabs(u0[2])) ? 0
              : (fabs(u0[1]) <= fabs(u0[2]) ? 1 : 2);
        double e[3] = {0.0, 0.0, 0.0}; e[m] = 1.0;
        double cx[3] = { u0[1]*e[2] - u0[2]*e[1],
                         u0[2]*e[0] - u0[0]*e[2],
                         u0[0]*e[1] - u0[1]*e[0] };
        double nn = sqrt(cx[0]*cx[0] + cx[1]*cx[1] + cx[2]*cx[2]);
#pragma unroll
        for (int a = 0; a < 3; ++a) u1[a] = cx[a] / nn;
    }
    u2[0] = u0[1]*u1[2] - u0[2]*u1[1];
    u2[1] = u0[2]*u1[0] - u0[0]*u1[2];
    u2[2] = u0[0]*u1[1] - u0[1]*u1[0];
    double d = v0[0]*(v1[1]*v2[2] - v1[2]*v2[1])
             - v0[1]*(v1[0]*v2[2] - v1[2]*v2[0])
             + v0[2]*(v1[0]*v2[1] - v1[1]*v2[0]);
#pragma unroll
    for (int a = 0; a < 3; ++a)
#pragma unroll
        for (int c = 0; c < 3; ++c)
            R[a][c] = v0[a]*u0[c] + v1[a]*u1[c] + d * (v2[a]*u2[c]);
}

// grid 79, block 256
__global__ void k_arap(const float* __restrict__ xyz1, const float* __restrict__ wmat,
                       const int* __restrict__ nbr, const int* __restrict__ nnum,
                       float* __restrict__ ws) {
    const float* recon = ws + OFF_V;
    float* gv = ws + OFF_GV;
    int i = blockIdx.x * 256 + threadIdx.x;
    double pv = 0.0;
    if (i < N_V) {
        int num = nnum[i];
        if (num > KNB) num = KNB;
        double cr0 = xyz1[3*i], cr1 = xyz1[3*i+1], cr2 = xyz1[3*i+2];
        double cd0 = recon[3*i], cd1 = recon[3*i+1], cd2 = recon[3*i+2];
        double S[3][3] = {{0,0,0},{0,0,0},{0,0,0}};
        for (int k = 0; k < num; ++k) {
            int j = nbr[i*KNB + k];
            double w = wmat[i*KNB + k];
            double er[3] = { xyz1[3*j] - cr0, xyz1[3*j+1] - cr1, xyz1[3*j+2] - cr2 };
            double ed[3] = { recon[3*j] - cd0, recon[3*j+1] - cd1, recon[3*j+2] - cd2 };
#pragma unroll
            for (int a = 0; a < 3; ++a)
#pragma unroll
                for (int b = 0; b < 3; ++b) S[a][b] += w * er[a] * ed[b];
        }
        double R[3][3];
        compute_R(S, R);
        const float gscale = 2.0f / (float)N_V;
        for (int k = 0; k < num; ++k) {
            int j = nbr[i*KNB + k];
            double w = wmat[i*KNB + k];
            double er[3] = { xyz1[3*j] - cr0, xyz1[3*j+1] - cr1, xyz1[3*j+2] - cr2 };
            double ed[3] = { recon[3*j] - cd0, recon[3*j+1] - cd1, recon[3*j+2] - cd2 };
            double rr0 = R[0][0]*er[0] + R[0][1]*er[1] + R[0][2]*er[2];
            double rr1 = R[1][0]*er[0] + R[1][1]*er[1] + R[1][2]*er[2];
            double rr2 = R[2][0]*er[0] + R[2][1]*er[1] + R[2][2]*er[2];
            double r0 = ed[0] - rr0, r1 = ed[1] - rr1, r2 = ed[2] - rr2;
            pv += w * (r0*r0 + r1*r1 + r2*r2);
            float g0 = gscale * (float)(w * r0);
            float g1 = gscale * (float)(w * r1);
            float g2 = gscale * (float)(w * r2);
            atomicAdd(&gv[3*j+0],  g0);
            atomicAdd(&gv[3*j+1],  g1);
            atomicAdd(&gv[3*j+2],  g2);
            atomicAdd(&gv[3*i+0], -g0);
            atomicAdd(&gv[3*i+1], -g1);
            atomicAdd(&gv[3*i+2], -g2);
        }
    }
    __shared__ double red[256];
    red[threadIdx.x] = pv;
    __syncthreads();
    for (int s = 128; s > 0; s >>= 1) {
        if (threadIdx.x < s) red[threadIdx.x] += red[threadIdx.x + s];
        __syncthreads();
    }
    if (threadIdx.x == 0)
        atomicAdd(reinterpret_cast<double*>(ws + OFF_E), red[0]);
}

// ---------------- backward ----------------

// grid 1024, block 256: g_z2[j] = (h2[j]>0) * dot(W3[j,:], g_v)
__global__ void k_gh2(const float* __restrict__ W3, float* __restrict__ ws) {
    int j = blockIdx.x;
    float* gz2 = ws + OFF_GZ2;
    float h2v = ws[OFF_H2 + j];
    if (h2v <= 0.f) {
        if (threadIdx.x == 0) gz2[j] = 0.f;
        return;
    }
    const float4* w3r = reinterpret_cast<const float4*>(W3 + (size_t)j * M3);
    const float4* gv4 = reinterpret_cast<const float4*>(ws + OFF_GV);
    float acc = 0.f;
    for (int it = threadIdx.x; it < M3 / 4; it += 256) {
        float4 a = w3r[it], b = gv4[it];
        acc += a.x*b.x + a.y*b.y + a.z*b.z + a.w*b.w;
    }
    for (int m = 32; m; m >>= 1) acc += __shfl_xor(acc, m);
    __shared__ float wsum[4];
    if ((threadIdx.x & 63) == 0) wsum[threadIdx.x >> 6] = acc;
    __syncthreads();
    if (threadIdx.x == 0) gz2[j] = wsum[0] + wsum[1] + wsum[2] + wsum[3];
}

// grid 128, block 256 (wave per row): g_z1[i] = (h1[i]>0) * dot(W2[i,:], g_z2)
__global__ void k_gh1(const float* __restrict__ W2, float* __restrict__ ws) {
    int wv = threadIdx.x >> 6, ln = threadIdx.x & 63;
    int i = blockIdx.x * 4 + wv;  // < 512
    const float* gz2 = ws + OFF_GZ2;
    float acc = 0.f;
#pragma unroll
    for (int it = 0; it < H2 / 64; ++it) {
        int jj = ln + it * 64;
        acc += W2[(size_t)i * H2 + jj] * gz2[jj];
    }
    for (int m = 32; m; m >>= 1) acc += __shfl_xor(acc, m);
    if (ln == 0) ws[OFF_GZ1 + i] = (ws[OFF_H1 + i] > 0.f) ? acc : 0.f;
}

// grid 64, block 256 (wave per row): out[1+d] = dot(W1[d,:], g_z1); out[0] = -E/N
__global__ void k_gcode(const float* __restrict__ W1, float* __restrict__ ws,
                        float* __restrict__ out) {
    int wv = threadIdx.x >> 6, ln = threadIdx.x & 63;
    int d = blockIdx.x * 4 + wv;  // < 256
    const float* gz1 = ws + OFF_GZ1;
    float acc = 0.f;
#pragma unroll
    for (int it = 0; it < H1 / 64; ++it) {
        int ii = ln + it * 64;
        acc += W1[(size_t)d * H1 + ii] * gz1[ii];
    }
    for (int m = 32; m; m >>= 1) acc += __shfl_xor(acc, m);
    if (ln == 0) out[1 + d] = acc;
    if (blockIdx.x == 0 && threadIdx.x == 0) {
        double E = *reinterpret_cast<const double*>(ws + OFF_E);
        out[0] = (float)(-(E / (double)N_V));
    }
}

extern "C" void kernel_launch(void* const* d_in, const int* in_sizes, int n_in,
                              void* d_out, int out_size, void* d_ws, size_t ws_size,
                              hipStream_t stream) {
    const float* code = (const float*)d_in[0];
    const float* xyz1 = (const float*)d_in[1];
    const float* wmat = (const float*)d_in[2];
    const float* W1   = (const float*)d_in[3];
    const float* b1   = (const float*)d_in[4];
    const float* W2   = (const float*)d_in[5];
    const float* b2   = (const float*)d_in[6];
    const float* W3   = (const float*)d_in[7];
    const float* b3   = (const float*)d_in[8];
    const int*   nbr  = (const int*)d_in[9];
    const int*   nnum = (const int*)d_in[10];
    float* out = (float*)d_out;
    float* ws  = (float*)d_ws;

    k_l1p    <<<dim3(2, 8),  256, 0, stream>>>(code, W1, ws);
    k_l2p    <<<dim3(4, 8),  256, 0, stream>>>(b1, W2, ws);
    k_compact<<<1,           256, 0, stream>>>(b2, ws);
    k_l3p    <<<dim3(59, 8), 256, 0, stream>>>(W3, ws);
    k_vred   <<<59,          256, 0, stream>>>(b3, ws);
    k_arap   <<<79,          256, 0, stream>>>(xyz1, wmat, nbr, nnum, ws);
    k_gh2    <<<1024,        256, 0, stream>>>(W3, ws);
    k_gh1    <<<128,         256, 0, stream>>>(W2, ws);
    k_gcode  <<<64,          256, 0, stream>>>(W1, ws, out);
}